// Round 3
// baseline (28696.057 us; speedup 1.0000x reference)
//
#include <hip/hip_runtime.h>
#include <cmath>

#define Tn 4096
#define Hn 1024
#define NHn 16
#define HDn 64
#define In 4096
#define Vn 1024
#define NSTEPSn 8

enum { EPI_NONE = 0, EPI_ADD = 1, EPI_SILU = 2, EPI_MUL = 3, EPI_BIAS = 4 };

// ---------------- RMSNorm (double accumulation, fp32 storage) ----------------
__global__ __launch_bounds__(256) void rmsnorm_kernel(const float* __restrict__ x,
                                                      const float* __restrict__ w,
                                                      float* __restrict__ y) {
    int t = blockIdx.x;
    const float4* xr = (const float4*)(x + (size_t)t * Hn);
    float4 v = xr[threadIdx.x];
    double ss = (double)v.x * v.x + (double)v.y * v.y + (double)v.z * v.z + (double)v.w * v.w;
#pragma unroll
    for (int o = 1; o < 64; o <<= 1) ss += __shfl_xor(ss, o, 64);
    __shared__ double red[4];
    if ((threadIdx.x & 63) == 0) red[threadIdx.x >> 6] = ss;
    __syncthreads();
    double tot = red[0] + red[1] + red[2] + red[3];
    double rs = 1.0 / sqrt(tot * (1.0 / Hn) + 1e-6);
    const float4* wr = (const float4*)w;
    float4 wv = wr[threadIdx.x];
    float4 o;
    o.x = (float)((double)v.x * rs * (double)wv.x);
    o.y = (float)((double)v.y * rs * (double)wv.y);
    o.z = (float)((double)v.z * rs * (double)wv.z);
    o.w = (float)((double)v.w * rs * (double)wv.w);
    ((float4*)(y + (size_t)t * Hn))[threadIdx.x] = o;
}

// ---------------- Attention: one wave per (t, head); f64 math ----------------
__global__ __launch_bounds__(256) void attn_kernel(const float* __restrict__ q,
                                                   const float* __restrict__ K0,
                                                   const float* __restrict__ V0,
                                                   const float* __restrict__ EK,
                                                   const float* __restrict__ EV,
                                                   const int* __restrict__ toks,
                                                   float* __restrict__ ctx, int p) {
    int wave = blockIdx.x * 4 + (threadIdx.x >> 6);  // t*NH + head
    int lane = threadIdx.x & 63;
    int t = wave >> 4;                    // NH = 16
    int col = ((wave & 15) << 6) | lane;  // h*64 + lane
    int i = lane & 31;
    int half = lane >> 5;
    size_t base = (size_t)wave * HDn + lane;

    // inv_freq = 10000^(-2i/64), f64
    double inv = exp(-((double)(2 * i) * (1.0 / (double)HDn)) * 9.210340371976184);

    // RoPE(q, pos=p)
    double qv = (double)q[base];
    double qpart = __shfl_xor(qv, 32, 64);
    double angp = (double)p * inv;
    double cp = cos(angp), sp = sin(angp);
    double qr = half ? (qv * cp + qpart * sp) : (qv * cp - qpart * sp);

    double sc[NSTEPSn];
    int tk[NSTEPSn];
    double m = -1e300;
    for (int j = 0; j <= p; j++) {
        double kr;
        if (j == 0) {
            kr = (double)K0[base];  // RoPE at pos 0 is identity
            tk[0] = 0;
        } else {
            int tok = toks[(size_t)t * NSTEPSn + (j - 1)];
            tk[j] = tok;
            double kv = (double)EK[(size_t)tok * Hn + col];
            double kpart = __shfl_xor(kv, 32, 64);
            double ang = (double)j * inv;
            double c = cos(ang), s = sin(ang);
            kr = half ? (kv * c + kpart * s) : (kv * c - kpart * s);
        }
        double pr = qr * kr;
#pragma unroll
        for (int o = 1; o < 64; o <<= 1) pr += __shfl_xor(pr, o, 64);
        sc[j] = pr * 0.125;  // 1/sqrt(64)
        m = fmax(m, sc[j]);
    }
    double den = 0.0;
    for (int j = 0; j <= p; j++) {
        sc[j] = exp(sc[j] - m);
        den += sc[j];
    }
    double invd = 1.0 / den;
    double acc = 0.0;
    for (int j = 0; j <= p; j++) {
        double vv = (j == 0) ? (double)V0[base] : (double)EV[(size_t)tk[j] * Hn + col];
        acc += sc[j] * vv;
    }
    ctx[base] = (float)(acc * invd);
}

// ---------------- GEMM: C(M x N) = A(M x K) @ B(K x N slice), f64 accumulate.
// fp32 A/B/aux storage; OutT = float or double. 64x64x16 tile, 4x4 micro.
template <int EPI, typename OutT>
__global__ __launch_bounds__(256) void gemm_kernel(const float* __restrict__ A,
                                                   const float* __restrict__ B,
                                                   OutT* C, const float* aux,
                                                   int N, int K, int ldb, int ldc) {
    const int BM = 64, BN = 64, BK = 16;
    __shared__ float As[BK][BM + 4];  // transposed A-tile
    __shared__ float Bs[BK][BN + 4];
    int tid = threadIdx.x;
    int tx = tid & 15, ty = tid >> 4;
    int bm = blockIdx.y, bn = blockIdx.x;
    const float* Ap = A + (size_t)bm * BM * K;
    const float* Bp = B + (size_t)bn * BN;
    double acc[4][4] = {};

    for (int k0 = 0; k0 < K; k0 += BK) {
        {
            int mi = tid >> 2, kq = (tid & 3) << 2;
            float4 av = *(const float4*)(Ap + (size_t)mi * K + k0 + kq);
            As[kq + 0][mi] = av.x;
            As[kq + 1][mi] = av.y;
            As[kq + 2][mi] = av.z;
            As[kq + 3][mi] = av.w;
            int kb = tid >> 4, nq = (tid & 15) << 2;
            float4 bv = *(const float4*)(Bp + (size_t)(k0 + kb) * ldb + nq);
            *(float4*)(&Bs[kb][nq]) = bv;
        }
        __syncthreads();
#pragma unroll
        for (int kk = 0; kk < BK; kk++) {
            float4 af = *(const float4*)(&As[kk][ty * 4]);
            float4 bf = *(const float4*)(&Bs[kk][tx * 4]);
            double a[4] = {(double)af.x, (double)af.y, (double)af.z, (double)af.w};
            double b[4] = {(double)bf.x, (double)bf.y, (double)bf.z, (double)bf.w};
#pragma unroll
            for (int ii = 0; ii < 4; ii++)
#pragma unroll
                for (int jj = 0; jj < 4; jj++) acc[ii][jj] = fma(a[ii], b[jj], acc[ii][jj]);
        }
        __syncthreads();
    }

    int m0 = bm * BM + ty * 4, n0 = bn * BN + tx * 4;
#pragma unroll
    for (int ii = 0; ii < 4; ii++) {
        size_t row = (size_t)(m0 + ii) * ldc + n0;
#pragma unroll
        for (int jj = 0; jj < 4; jj++) {
            double v = acc[ii][jj];
            if (EPI == EPI_ADD) v += (double)aux[row + jj];
            if (EPI == EPI_SILU) v = v / (1.0 + exp(-v));
            if (EPI == EPI_MUL) v *= (double)aux[row + jj];
            if (EPI == EPI_BIAS) v += (double)aux[n0 + jj];
            C[row + jj] = (OutT)v;
        }
    }
}

// ---------------- Argmax over f64 logits (first-max tie-break) ----------------
__global__ __launch_bounds__(256) void argmax_kernel(const double* __restrict__ logits,
                                                     int* __restrict__ out_tok, int p) {
    int t = blockIdx.x;
    const double* lr = logits + (size_t)t * Vn;
    double bv = -1e300;
    int bi = 0x7fffffff;
    for (int j = threadIdx.x; j < Vn; j += 256) {
        double v = lr[j];
        if (v > bv || (v == bv && j < bi)) {
            bv = v;
            bi = j;
        }
    }
#pragma unroll
    for (int o = 1; o < 64; o <<= 1) {
        double ov = __shfl_xor(bv, o, 64);
        int oi = __shfl_xor(bi, o, 64);
        if (ov > bv || (ov == bv && oi < bi)) {
            bv = ov;
            bi = oi;
        }
    }
    __shared__ double sv[4];
    __shared__ int si[4];
    if ((threadIdx.x & 63) == 0) {
        sv[threadIdx.x >> 6] = bv;
        si[threadIdx.x >> 6] = bi;
    }
    __syncthreads();
    if (threadIdx.x == 0) {
        for (int w = 1; w < 4; w++) {
            if (sv[w] > bv || (sv[w] == bv && si[w] < bi)) {
                bv = sv[w];
                bi = si[w];
            }
        }
        out_tok[(size_t)t * NSTEPSn + p] = bi;
    }
}

// ---------------- Embedding gather ----------------
__global__ __launch_bounds__(256) void embed_kernel(const float* __restrict__ E,
                                                    const int* __restrict__ toks,
                                                    float* __restrict__ x, int p) {
    int t = blockIdx.x;
    int tok = toks[(size_t)t * NSTEPSn + p];
    float4 v = ((const float4*)(E + (size_t)tok * Hn))[threadIdx.x];
    ((float4*)(x + (size_t)t * Hn))[threadIdx.x] = v;
}

extern "C" void kernel_launch(void* const* d_in, const int* in_sizes, int n_in,
                              void* d_out, int out_size, void* d_ws, size_t ws_size,
                              hipStream_t stream) {
    const float* x0 = (const float*)d_in[0];
    const float* Wq = (const float*)d_in[1];
    const float* Wk = (const float*)d_in[2];
    const float* Wv = (const float*)d_in[3];
    const float* Wo = (const float*)d_in[4];
    const float* Wg = (const float*)d_in[5];
    const float* Wu = (const float*)d_in[6];
    const float* Wd = (const float*)d_in[7];
    const float* n1 = (const float*)d_in[8];
    const float* n2 = (const float*)d_in[9];
    const float* Emb = (const float*)d_in[10];
    const float* Wout = (const float*)d_in[11];
    const float* bout = (const float*)d_in[12];
    int* toks = (int*)d_out;

    float* ws = (float*)d_ws;
    const size_t SZH = (size_t)Tn * Hn;  // 4M floats
    const size_t SVH = (size_t)Vn * Hn;  // 1M floats
    float* En = ws;                         // rmsnorm(E)      4MB
    float* EK = ws + SVH;                   // En @ Wk         4MB
    float* EV = ws + 2 * SVH;               // En @ Wv         4MB
    float* K0 = ws + 3 * SVH;               // pos-0 K         16MB
    float* V0 = ws + 3 * SVH + SZH;         // pos-0 V         16MB
    float* xb = ws + 3 * SVH + 2 * SZH;     // embedding / h2  16MB
    float* xn = ws + 3 * SVH + 3 * SZH;     // rmsnorm out     16MB
    float* qb = ws + 3 * SVH + 4 * SZH;     // q / MLP accum   16MB
    float* Gc = ws + 3 * SVH + 5 * SZH;     // MLP chunk       16MB
    float* cx = ws + 3 * SVH + 6 * SZH;     // ctx (fp32), shares region with logits
    double* logitsD = (double*)(ws + 3 * SVH + 6 * SZH);  // T x V doubles, 32MB
    // total = 3*SVH + 6*SZH + 8M floats = 35M floats = 140 MB

    dim3 blk(256);
    dim3 gTH(Hn / 64, Tn / 64);  // (16, 64)
    dim3 gVH(Hn / 64, Vn / 64);  // (16, 16)

    // ---- Precompute embedding-derived K/V tables ----
    rmsnorm_kernel<<<Vn, 256, 0, stream>>>(Emb, n1, En);
    gemm_kernel<EPI_NONE, float><<<gVH, blk, 0, stream>>>(En, Wk, EK, nullptr, Hn, Hn, Hn, Hn);
    gemm_kernel<EPI_NONE, float><<<gVH, blk, 0, stream>>>(En, Wv, EV, nullptr, Hn, Hn, Hn, Hn);

    const int IC = 1024;  // MLP chunk width
    dim3 gIc(IC / 64, Tn / 64);

    for (int p = 0; p < NSTEPSn; p++) {
        const float* src = (p == 0) ? x0 : xb;

        rmsnorm_kernel<<<Tn, 256, 0, stream>>>(src, n1, xn);
        gemm_kernel<EPI_NONE, float><<<gTH, blk, 0, stream>>>(xn, Wq, qb, nullptr, Hn, Hn, Hn, Hn);
        if (p == 0) {
            gemm_kernel<EPI_NONE, float><<<gTH, blk, 0, stream>>>(xn, Wk, K0, nullptr, Hn, Hn, Hn, Hn);
            gemm_kernel<EPI_NONE, float><<<gTH, blk, 0, stream>>>(xn, Wv, V0, nullptr, Hn, Hn, Hn, Hn);
        }
        attn_kernel<<<(Tn * NHn) / 4, 256, 0, stream>>>(qb, K0, V0, EK, EV, toks, cx, p);
        // h2 = ctx @ Wo + src
        gemm_kernel<EPI_ADD, float><<<gTH, blk, 0, stream>>>(cx, Wo, xb, src, Hn, Hn, Hn, Hn);
        rmsnorm_kernel<<<Tn, 256, 0, stream>>>(xb, n2, xn);
        // Gated MLP, chunked over I; accumulate into qb.
        for (int c = 0; c < In / IC; c++) {
            gemm_kernel<EPI_SILU, float><<<gIc, blk, 0, stream>>>(
                xn, Wg + c * IC, Gc, nullptr, IC, Hn, In, IC);
            gemm_kernel<EPI_MUL, float><<<gIc, blk, 0, stream>>>(
                xn, Wu + c * IC, Gc, Gc, IC, Hn, In, IC);
            gemm_kernel<EPI_ADD, float><<<gTH, blk, 0, stream>>>(
                Gc, Wd + (size_t)c * IC * Hn, qb, (c == 0) ? xb : qb, Hn, IC, Hn, Hn);
        }
        // logits (double) = out @ Wout + bout
        gemm_kernel<EPI_BIAS, double><<<gTH, blk, 0, stream>>>(qb, Wout, logitsD, bout, Vn, Hn, Vn, Vn);
        argmax_kernel<<<Tn, 256, 0, stream>>>(logitsD, toks, p);
        if (p < NSTEPSn - 1) embed_kernel<<<Tn, 256, 0, stream>>>(Emb, toks, xb, p);
    }
}

// Round 4
// 12908.257 us; speedup vs baseline: 2.2231x; 2.2231x over previous
//
#include <hip/hip_runtime.h>
#include <cmath>

#define Tn 4096
#define Hn 1024
#define NHn 16
#define HDn 64
#define In 4096
#define Vn 1024
#define NSTEPSn 8

enum { EPI_NONE = 0, EPI_ADD = 1, EPI_SILU = 2, EPI_MUL = 3, EPI_BIAS = 4 };

typedef __attribute__((ext_vector_type(8))) short bf16x8;
typedef __attribute__((ext_vector_type(4))) float f32x4;

__device__ inline unsigned short bf16rne(float x) {
    unsigned int u = __float_as_uint(x);
    u += 0x7fff + ((u >> 16) & 1);
    return (unsigned short)(u >> 16);
}
__device__ inline float bf2f(unsigned short h) {
    return __uint_as_float(((unsigned int)h) << 16);
}
__device__ inline void split3(float x, unsigned short& h, unsigned short& m,
                              unsigned short& l) {
    h = bf16rne(x);
    float r = x - bf2f(h);
    m = bf16rne(r);
    float r2 = r - bf2f(m);
    l = bf16rne(r2);
}

// ---------------- RMSNorm -> bf16 triple planes (f64 math) ----------------
__global__ __launch_bounds__(256) void rmsnorm3_kernel(const float* __restrict__ x,
                                                       const float* __restrict__ w,
                                                       unsigned short* __restrict__ y3,
                                                       size_t stride) {
    int t = blockIdx.x;
    const float4* xr = (const float4*)(x + (size_t)t * Hn);
    float4 v = xr[threadIdx.x];
    double ss = (double)v.x * v.x + (double)v.y * v.y + (double)v.z * v.z + (double)v.w * v.w;
#pragma unroll
    for (int o = 1; o < 64; o <<= 1) ss += __shfl_xor(ss, o, 64);
    __shared__ double red[4];
    if ((threadIdx.x & 63) == 0) red[threadIdx.x >> 6] = ss;
    __syncthreads();
    double tot = red[0] + red[1] + red[2] + red[3];
    double rs = 1.0 / sqrt(tot * (1.0 / Hn) + 1e-6);
    const float4* wr = (const float4*)w;
    float4 wv = wr[threadIdx.x];
    float o[4];
    o[0] = (float)((double)v.x * rs * (double)wv.x);
    o[1] = (float)((double)v.y * rs * (double)wv.y);
    o[2] = (float)((double)v.z * rs * (double)wv.z);
    o[3] = (float)((double)v.w * rs * (double)wv.w);
    ushort4 hq, mq, lq;
    split3(o[0], hq.x, mq.x, lq.x);
    split3(o[1], hq.y, mq.y, lq.y);
    split3(o[2], hq.z, mq.z, lq.z);
    split3(o[3], hq.w, mq.w, lq.w);
    size_t off = (size_t)t * Hn + threadIdx.x * 4;
    *(ushort4*)(y3 + off) = hq;
    *(ushort4*)(y3 + stride + off) = mq;
    *(ushort4*)(y3 + 2 * stride + off) = lq;
}

// ---------------- Attention (f64 math), output bf16 triple ----------------
__global__ __launch_bounds__(256) void attn_kernel(const float* __restrict__ q,
                                                   const float* __restrict__ K0,
                                                   const float* __restrict__ V0,
                                                   const float* __restrict__ EK,
                                                   const float* __restrict__ EV,
                                                   const int* __restrict__ toks,
                                                   unsigned short* __restrict__ ctx3,
                                                   size_t stride, int p) {
    int wave = blockIdx.x * 4 + (threadIdx.x >> 6);  // t*NH + head
    int lane = threadIdx.x & 63;
    int t = wave >> 4;
    int col = ((wave & 15) << 6) | lane;
    int i = lane & 31;
    int half = lane >> 5;
    size_t base = (size_t)wave * HDn + lane;

    double inv = exp(-((double)(2 * i) * (1.0 / (double)HDn)) * 9.210340371976184);

    double qv = (double)q[base];
    double qpart = __shfl_xor(qv, 32, 64);
    double angp = (double)p * inv;
    double cp = cos(angp), sp = sin(angp);
    double qr = half ? (qv * cp + qpart * sp) : (qv * cp - qpart * sp);

    double sc[NSTEPSn];
    int tk[NSTEPSn];
    double m = -1e300;
    for (int j = 0; j <= p; j++) {
        double kr;
        if (j == 0) {
            kr = (double)K0[base];
            tk[0] = 0;
        } else {
            int tok = toks[(size_t)t * NSTEPSn + (j - 1)];
            tk[j] = tok;
            double kv = (double)EK[(size_t)tok * Hn + col];
            double kpart = __shfl_xor(kv, 32, 64);
            double ang = (double)j * inv;
            double c = cos(ang), s = sin(ang);
            kr = half ? (kv * c + kpart * s) : (kv * c - kpart * s);
        }
        double pr = qr * kr;
#pragma unroll
        for (int o = 1; o < 64; o <<= 1) pr += __shfl_xor(pr, o, 64);
        sc[j] = pr * 0.125;
        m = fmax(m, sc[j]);
    }
    double den = 0.0;
    for (int j = 0; j <= p; j++) {
        sc[j] = exp(sc[j] - m);
        den += sc[j];
    }
    double invd = 1.0 / den;
    double acc = 0.0;
    for (int j = 0; j <= p; j++) {
        double vv = (j == 0) ? (double)V0[base] : (double)EV[(size_t)tk[j] * Hn + col];
        acc += sc[j] * vv;
    }
    unsigned short h, mm, l;
    split3((float)(acc * invd), h, mm, l);
    ctx3[base] = h;
    ctx3[stride + base] = mm;
    ctx3[2 * stride + base] = l;
}

// ---------------- bf16x3 MFMA GEMM with f64 chunk accumulation ----------------
// C(M x N) = A(M x K) @ B(K x N). A pre-split bf16 planes [3][M][K] (k-contig).
// B fp32 [K][N] (ldb), split+transposed to LDS on the fly.
// Block: 128(M) x 64(N), 256 thr = 4 waves (2x2), wave = 64x32 (4x2 tiles 16x16).
// MFMA 16x16x32 bf16: A[m=lane&15][k=(lane>>4)*8+j]; C/D col=lane&15,
// row=(lane>>4)*4+reg. Promote fp32 acc -> f64 every 2 K-chunks (K'=64).
template <int EPI, bool TRIPLE>
__global__ __launch_bounds__(256, 2) void gemm3_kernel(
    const unsigned short* __restrict__ A3, size_t strideA,
    const float* __restrict__ B, int ldb,
    float* Cf, unsigned short* C3, size_t strideC,
    const float* aux, int K, int ldc) {
    __shared__ unsigned short As[3][128][40];  // [plane][m][k], +8 pad
    __shared__ unsigned short Bs[3][64][40];   // [plane][n][k], +8 pad

    int tid = threadIdx.x;
    int wv = tid >> 6, lane = tid & 63;
    int wr = wv >> 1, wc = wv & 1;
    int mblk = blockIdx.y * 128, nblk = blockIdx.x * 64;

    f32x4 acc[4][2];
    double accd[4][2][4];
#pragma unroll
    for (int mt = 0; mt < 4; mt++)
#pragma unroll
        for (int nt = 0; nt < 2; nt++) {
            acc[mt][nt] = (f32x4){0.f, 0.f, 0.f, 0.f};
#pragma unroll
            for (int r = 0; r < 4; r++) accd[mt][nt][r] = 0.0;
        }

    int rA = lane & 15;
    int kq = (lane >> 4) << 3;

    for (int k0 = 0, c = 0; k0 < K; k0 += 32, ++c) {
        // ---- stage A: copy pre-split bf16 planes (k-contiguous, b128) ----
#pragma unroll
        for (int pl = 0; pl < 3; pl++) {
#pragma unroll
            for (int r = 0; r < 2; r++) {
                int idx = tid + r * 256;          // 0..511
                int row = idx >> 2, kg = (idx & 3) << 3;
                const unsigned short* src =
                    A3 + (size_t)pl * strideA + (size_t)(mblk + row) * K + k0 + kg;
                *(uint4*)(&As[pl][row][kg]) = *(const uint4*)src;
            }
        }
        // ---- stage B: load fp32, split to 3 bf16, transpose to [n][k] ----
#pragma unroll
        for (int r = 0; r < 2; r++) {
            int idx = tid + r * 256;  // 0..511
            int kk = idx >> 4, ng = (idx & 15) << 2;
            float4 bv = *(const float4*)(B + (size_t)(k0 + kk) * ldb + nblk + ng);
            float xv[4] = {bv.x, bv.y, bv.z, bv.w};
#pragma unroll
            for (int cc = 0; cc < 4; cc++) {
                unsigned short h, m, l;
                split3(xv[cc], h, m, l);
                Bs[0][ng + cc][kk] = h;
                Bs[1][ng + cc][kk] = m;
                Bs[2][ng + cc][kk] = l;
            }
        }
        __syncthreads();

        // ---- fragments ----
        bf16x8 Af[3][4], Bf[3][2];
#pragma unroll
        for (int pl = 0; pl < 3; pl++) {
#pragma unroll
            for (int mt = 0; mt < 4; mt++)
                Af[pl][mt] = *(const bf16x8*)(&As[pl][wr * 64 + mt * 16 + rA][kq]);
#pragma unroll
            for (int nt = 0; nt < 2; nt++)
                Bf[pl][nt] = *(const bf16x8*)(&Bs[pl][wc * 32 + nt * 16 + rA][kq]);
        }
        // ---- 6 MFMA products per tile ----
#pragma unroll
        for (int mt = 0; mt < 4; mt++)
#pragma unroll
            for (int nt = 0; nt < 2; nt++) {
                f32x4 a = acc[mt][nt];
                a = __builtin_amdgcn_mfma_f32_16x16x32_bf16(Af[0][mt], Bf[0][nt], a, 0, 0, 0);
                a = __builtin_amdgcn_mfma_f32_16x16x32_bf16(Af[0][mt], Bf[1][nt], a, 0, 0, 0);
                a = __builtin_amdgcn_mfma_f32_16x16x32_bf16(Af[1][mt], Bf[0][nt], a, 0, 0, 0);
                a = __builtin_amdgcn_mfma_f32_16x16x32_bf16(Af[1][mt], Bf[1][nt], a, 0, 0, 0);
                a = __builtin_amdgcn_mfma_f32_16x16x32_bf16(Af[0][mt], Bf[2][nt], a, 0, 0, 0);
                a = __builtin_amdgcn_mfma_f32_16x16x32_bf16(Af[2][mt], Bf[0][nt], a, 0, 0, 0);
                acc[mt][nt] = a;
            }
        __syncthreads();

        // ---- promote fp32 -> f64 every 2 chunks (K'=64) ----
        if (c & 1) {
#pragma unroll
            for (int mt = 0; mt < 4; mt++)
#pragma unroll
                for (int nt = 0; nt < 2; nt++)
#pragma unroll
                    for (int r = 0; r < 4; r++) {
                        accd[mt][nt][r] += (double)acc[mt][nt][r];
                        acc[mt][nt][r] = 0.f;
                    }
        }
    }

    // ---- epilogue (f64), write f32 or bf16-triple ----
#pragma unroll
    for (int mt = 0; mt < 4; mt++)
#pragma unroll
        for (int nt = 0; nt < 2; nt++) {
            int n = nblk + wc * 32 + nt * 16 + (lane & 15);
            int mb = mblk + wr * 64 + mt * 16 + ((lane >> 4) << 2);
#pragma unroll
            for (int r = 0; r < 4; r++) {
                int m = mb + r;
                size_t off = (size_t)m * ldc + n;
                double v = accd[mt][nt][r];
                if (EPI == EPI_ADD) v += (double)aux[off];
                if (EPI == EPI_SILU) {
                    float vf = (float)v;
                    v = (double)(vf / (1.0f + expf(-vf)));
                }
                if (EPI == EPI_MUL) v *= (double)aux[off];
                if (EPI == EPI_BIAS) v += (double)aux[n];
                if (TRIPLE) {
                    unsigned short h, mm, l;
                    split3((float)v, h, mm, l);
                    C3[off] = h;
                    C3[strideC + off] = mm;
                    C3[2 * strideC + off] = l;
                } else {
                    Cf[off] = (float)v;
                }
            }
        }
}

// ---------------- Argmax over f32 logits (first-max tie-break) ----------------
__global__ __launch_bounds__(256) void argmax_kernel(const float* __restrict__ logits,
                                                     int* __restrict__ out_tok, int p) {
    int t = blockIdx.x;
    const float* lr = logits + (size_t)t * Vn;
    float bv = -INFINITY;
    int bi = 0x7fffffff;
    for (int j = threadIdx.x; j < Vn; j += 256) {
        float v = lr[j];
        if (v > bv || (v == bv && j < bi)) {
            bv = v;
            bi = j;
        }
    }
#pragma unroll
    for (int o = 1; o < 64; o <<= 1) {
        float ov = __shfl_xor(bv, o, 64);
        int oi = __shfl_xor(bi, o, 64);
        if (ov > bv || (ov == bv && oi < bi)) {
            bv = ov;
            bi = oi;
        }
    }
    __shared__ float sv[4];
    __shared__ int si[4];
    if ((threadIdx.x & 63) == 0) {
        sv[threadIdx.x >> 6] = bv;
        si[threadIdx.x >> 6] = bi;
    }
    __syncthreads();
    if (threadIdx.x == 0) {
        for (int w = 1; w < 4; w++) {
            if (sv[w] > bv || (sv[w] == bv && si[w] < bi)) {
                bv = sv[w];
                bi = si[w];
            }
        }
        out_tok[(size_t)t * NSTEPSn + p] = bi;
    }
}

// ---------------- Embedding gather ----------------
__global__ __launch_bounds__(256) void embed_kernel(const float* __restrict__ E,
                                                    const int* __restrict__ toks,
                                                    float* __restrict__ x, int p) {
    int t = blockIdx.x;
    int tok = toks[(size_t)t * NSTEPSn + p];
    float4 v = ((const float4*)(E + (size_t)tok * Hn))[threadIdx.x];
    ((float4*)(x + (size_t)t * Hn))[threadIdx.x] = v;
}

extern "C" void kernel_launch(void* const* d_in, const int* in_sizes, int n_in,
                              void* d_out, int out_size, void* d_ws, size_t ws_size,
                              hipStream_t stream) {
    const float* x0 = (const float*)d_in[0];
    const float* Wq = (const float*)d_in[1];
    const float* Wk = (const float*)d_in[2];
    const float* Wv = (const float*)d_in[3];
    const float* Wo = (const float*)d_in[4];
    const float* Wg = (const float*)d_in[5];
    const float* Wu = (const float*)d_in[6];
    const float* Wd = (const float*)d_in[7];
    const float* n1 = (const float*)d_in[8];
    const float* n2 = (const float*)d_in[9];
    const float* Emb = (const float*)d_in[10];
    const float* Wout = (const float*)d_in[11];
    const float* bout = (const float*)d_in[12];
    int* toks = (int*)d_out;

    float* ws = (float*)d_ws;
    const size_t M1 = 1024 * 1024;
    float* EK = ws;                 // V x H fp32        4MB
    float* EV = ws + 1 * M1;        //                   4MB
    float* K0 = ws + 2 * M1;        // T x H fp32        16MB
    float* V0 = ws + 6 * M1;        //                   16MB
    float* xb = ws + 10 * M1;       // residual hidden   16MB
    float* qb = ws + 14 * M1;       // q / MLP acc / logits 16MB
    float* Gc = ws + 18 * M1;       // silu chunk        16MB
    unsigned short* s3a = (unsigned short*)(ws + 22 * M1);  // triple T x H, 24MB
    unsigned short* s3g = (unsigned short*)(ws + 28 * M1);  // triple T x 1024, 24MB
    // total 34M floats = 136 MB

    const size_t STH = (size_t)Tn * Hn;   // plane stride for T x 1024 triples
    const size_t SVH = (size_t)Vn * Hn;   // plane stride for V x H triple

    dim3 blk(256);
    dim3 gTH(Hn / 64, Tn / 128);  // (16, 32): M=T, N=1024
    dim3 gVH(Hn / 64, Vn / 128);  // (16, 8):  M=V, N=1024

    // ---- Precompute embedding-derived K/V tables ----
    rmsnorm3_kernel<<<Vn, 256, 0, stream>>>(Emb, n1, s3a, SVH);
    gemm3_kernel<EPI_NONE, false><<<gVH, blk, 0, stream>>>(
        s3a, SVH, Wk, Hn, EK, nullptr, 0, nullptr, Hn, Hn);
    gemm3_kernel<EPI_NONE, false><<<gVH, blk, 0, stream>>>(
        s3a, SVH, Wv, Hn, EV, nullptr, 0, nullptr, Hn, Hn);

    for (int p = 0; p < NSTEPSn; p++) {
        const float* src = (p == 0) ? x0 : xb;

        rmsnorm3_kernel<<<Tn, 256, 0, stream>>>(src, n1, s3a, STH);
        gemm3_kernel<EPI_NONE, false><<<gTH, blk, 0, stream>>>(
            s3a, STH, Wq, Hn, qb, nullptr, 0, nullptr, Hn, Hn);
        if (p == 0) {
            gemm3_kernel<EPI_NONE, false><<<gTH, blk, 0, stream>>>(
                s3a, STH, Wk, Hn, K0, nullptr, 0, nullptr, Hn, Hn);
            gemm3_kernel<EPI_NONE, false><<<gTH, blk, 0, stream>>>(
                s3a, STH, Wv, Hn, V0, nullptr, 0, nullptr, Hn, Hn);
        }
        attn_kernel<<<(Tn * NHn) / 4, 256, 0, stream>>>(qb, K0, V0, EK, EV, toks,
                                                        s3a, STH, p);
        // h2 = ctx @ Wo + src  (in-place into xb when src == xb)
        gemm3_kernel<EPI_ADD, false><<<gTH, blk, 0, stream>>>(
            s3a, STH, Wo, Hn, xb, nullptr, 0, src, Hn, Hn);
        rmsnorm3_kernel<<<Tn, 256, 0, stream>>>(xb, n2, s3a, STH);
        // Gated MLP, chunked over I (4 x 1024); accumulate into qb; final
        // chunk writes triple of 'out' into s3a.
        for (int c = 0; c < 4; c++) {
            gemm3_kernel<EPI_SILU, false><<<gTH, blk, 0, stream>>>(
                s3a, STH, Wg + c * 1024, In, Gc, nullptr, 0, nullptr, Hn, 1024);
            gemm3_kernel<EPI_MUL, true><<<gTH, blk, 0, stream>>>(
                s3a, STH, Wu + c * 1024, In, nullptr, s3g, STH, Gc, Hn, 1024);
            if (c < 3) {
                gemm3_kernel<EPI_ADD, false><<<gTH, blk, 0, stream>>>(
                    s3g, STH, Wd + (size_t)c * 1024 * Hn, Hn, qb, nullptr, 0,
                    (c == 0) ? xb : qb, 1024, Hn);
            } else {
                gemm3_kernel<EPI_ADD, true><<<gTH, blk, 0, stream>>>(
                    s3g, STH, Wd + (size_t)c * 1024 * Hn, Hn, nullptr, s3a, STH,
                    qb, 1024, Hn);
            }
        }
        // logits = out @ Wout + bout  (into qb)
        gemm3_kernel<EPI_BIAS, false><<<gTH, blk, 0, stream>>>(
            s3a, STH, Wout, Vn, qb, nullptr, 0, bout, Hn, Vn);
        argmax_kernel<<<Tn, 256, 0, stream>>>(qb, toks, p);
        if (p < NSTEPSn - 1) embed_kernel<<<Tn, 256, 0, stream>>>(Emb, toks, xb, p);
    }
}

// Round 5
// 9787.197 us; speedup vs baseline: 2.9320x; 1.3189x over previous
//
#include <hip/hip_runtime.h>
#include <cmath>

#define Tn 4096
#define Hn 1024
#define NHn 16
#define HDn 64
#define In 4096
#define Vn 1024
#define NSTEPSn 8

enum { EPI_NONE = 0, EPI_ADD = 1, EPI_SILU = 2, EPI_MUL = 3, EPI_BIAS = 4 };

typedef __attribute__((ext_vector_type(8))) short bf16x8;
typedef __attribute__((ext_vector_type(4))) float f32x4;

__device__ inline unsigned short bf16rne(float x) {
    unsigned int u = __float_as_uint(x);
    u += 0x7fff + ((u >> 16) & 1);
    return (unsigned short)(u >> 16);
}
__device__ inline float bf2f(unsigned short h) {
    return __uint_as_float(((unsigned int)h) << 16);
}
__device__ inline void split3(float x, unsigned short& h, unsigned short& m,
                              unsigned short& l) {
    h = bf16rne(x);
    float r = x - bf2f(h);
    m = bf16rne(r);
    float r2 = r - bf2f(m);
    l = bf16rne(r2);
}

// ---------------- RoPE cos/sin table: tab[j*32+i] = {cos(j*inv_i), sin(j*inv_i)}
__global__ void rope_tab_kernel(double2* __restrict__ tab) {
    int tid = threadIdx.x;  // 256 threads
    int j = tid >> 5, i = tid & 31;
    double inv = exp(-((double)(2 * i) * (1.0 / (double)HDn)) * 9.210340371976184);
    double ang = (double)j * inv;
    double2 cs;
    cs.x = cos(ang);
    cs.y = sin(ang);
    tab[tid] = cs;
}

// ---------------- Weight pre-split: W[K][N] fp32 -> W3[3][N][K] bf16 ----------------
__global__ __launch_bounds__(256) void presplit_kernel(const float* __restrict__ W,
                                                       unsigned short* __restrict__ W3,
                                                       int K, int N) {
    __shared__ float S[64][65];
    int k0 = blockIdx.y * 64, n0 = blockIdx.x * 64;
    int tid = threadIdx.x;
#pragma unroll
    for (int r = 0; r < 4; r++) {
        int idx = tid + r * 256;
        int kr = idx >> 4, c4 = (idx & 15) << 2;
        float4 v = *(const float4*)(W + (size_t)(k0 + kr) * N + n0 + c4);
        S[kr][c4] = v.x;
        S[kr][c4 + 1] = v.y;
        S[kr][c4 + 2] = v.z;
        S[kr][c4 + 3] = v.w;
    }
    __syncthreads();
    size_t PS = (size_t)N * K;
#pragma unroll
    for (int r = 0; r < 4; r++) {
        int idx = tid + r * 256;
        int kq = idx & 15, n = idx >> 4;
        ushort4 hq, mq, lq;
        split3(S[4 * kq + 0][n], hq.x, mq.x, lq.x);
        split3(S[4 * kq + 1][n], hq.y, mq.y, lq.y);
        split3(S[4 * kq + 2][n], hq.z, mq.z, lq.z);
        split3(S[4 * kq + 3][n], hq.w, mq.w, lq.w);
        size_t off = (size_t)(n0 + n) * K + k0 + 4 * kq;
        *(ushort4*)(W3 + off) = hq;
        *(ushort4*)(W3 + PS + off) = mq;
        *(ushort4*)(W3 + 2 * PS + off) = lq;
    }
}

// ---------------- RMSNorm -> bf16 triple planes (f64 math) ----------------
__global__ __launch_bounds__(256) void rmsnorm3_kernel(const float* __restrict__ x,
                                                       const float* __restrict__ w,
                                                       unsigned short* __restrict__ y3,
                                                       size_t stride) {
    int t = blockIdx.x;
    const float4* xr = (const float4*)(x + (size_t)t * Hn);
    float4 v = xr[threadIdx.x];
    double ss = (double)v.x * v.x + (double)v.y * v.y + (double)v.z * v.z + (double)v.w * v.w;
#pragma unroll
    for (int o = 1; o < 64; o <<= 1) ss += __shfl_xor(ss, o, 64);
    __shared__ double red[4];
    if ((threadIdx.x & 63) == 0) red[threadIdx.x >> 6] = ss;
    __syncthreads();
    double tot = red[0] + red[1] + red[2] + red[3];
    double rs = 1.0 / sqrt(tot * (1.0 / Hn) + 1e-6);
    const float4* wr = (const float4*)w;
    float4 wv = wr[threadIdx.x];
    float o[4];
    o[0] = (float)((double)v.x * rs * (double)wv.x);
    o[1] = (float)((double)v.y * rs * (double)wv.y);
    o[2] = (float)((double)v.z * rs * (double)wv.z);
    o[3] = (float)((double)v.w * rs * (double)wv.w);
    ushort4 hq, mq, lq;
    split3(o[0], hq.x, mq.x, lq.x);
    split3(o[1], hq.y, mq.y, lq.y);
    split3(o[2], hq.z, mq.z, lq.z);
    split3(o[3], hq.w, mq.w, lq.w);
    size_t off = (size_t)t * Hn + threadIdx.x * 4;
    *(ushort4*)(y3 + off) = hq;
    *(ushort4*)(y3 + stride + off) = mq;
    *(ushort4*)(y3 + 2 * stride + off) = lq;
}

// ---------------- Attention (f64 dot, table RoPE, f32 exp), out bf16 triple ----
__global__ __launch_bounds__(256) void attn_kernel(const float* __restrict__ q,
                                                   const float* __restrict__ K0,
                                                   const float* __restrict__ V0,
                                                   const float* __restrict__ EK,
                                                   const float* __restrict__ EV,
                                                   const int* __restrict__ toks,
                                                   const double2* __restrict__ tab,
                                                   unsigned short* __restrict__ ctx3,
                                                   size_t stride, int p) {
    int wave = blockIdx.x * 4 + (threadIdx.x >> 6);  // t*NH + head
    int lane = threadIdx.x & 63;
    int t = wave >> 4;
    int col = ((wave & 15) << 6) | lane;
    int i = lane & 31;
    int half = lane >> 5;
    size_t base = (size_t)wave * HDn + lane;

    // RoPE(q, pos=p) via table
    double2 csp = tab[p * 32 + i];
    double qv = (double)q[base];
    double qpart = __shfl_xor(qv, 32, 64);
    double qr = half ? (qv * csp.x + qpart * csp.y) : (qv * csp.x - qpart * csp.y);

    double sc[NSTEPSn];
    int tk[NSTEPSn];
    double m = -1e300;
    for (int j = 0; j <= p; j++) {
        double kr;
        if (j == 0) {
            kr = (double)K0[base];  // RoPE at pos 0 is identity
            tk[0] = 0;
        } else {
            int tok = toks[(size_t)t * NSTEPSn + (j - 1)];
            tk[j] = tok;
            double kv = (double)EK[(size_t)tok * Hn + col];
            double kpart = __shfl_xor(kv, 32, 64);
            double2 cs = tab[j * 32 + i];
            kr = half ? (kv * cs.x + kpart * cs.y) : (kv * cs.x - kpart * cs.y);
        }
        double pr = qr * kr;
#pragma unroll
        for (int o = 1; o < 64; o <<= 1) pr += __shfl_xor(pr, o, 64);
        sc[j] = pr * 0.125;
        m = fmax(m, sc[j]);
    }
    double den = 0.0;
    for (int j = 0; j <= p; j++) {
        sc[j] = (double)expf((float)(sc[j] - m));
        den += sc[j];
    }
    double invd = 1.0 / den;
    double acc = 0.0;
    for (int j = 0; j <= p; j++) {
        double vv = (j == 0) ? (double)V0[base] : (double)EV[(size_t)tk[j] * Hn + col];
        acc += sc[j] * vv;
    }
    unsigned short h, mm, l;
    split3((float)(acc * invd), h, mm, l);
    ctx3[base] = h;
    ctx3[stride + base] = mm;
    ctx3[2 * stride + base] = l;
}

// ---------------- bf16x3 MFMA GEMM with f64 chunk accumulation ----------------
// C(M x N) = A(M x K) @ B(K x N). A pre-split planes [3][M][K] (k-contig).
// PRE=true: B pre-split [3][N][K] planes (ldbk = row stride in elems).
// PRE=false: B fp32 [K][N] (ldb), split+transposed to LDS on the fly.
// Block: 128(M) x 64(N), 4 waves (2x2), wave = 4x2 tiles of 16x16.
// Promote fp32 acc -> f64 every 2 K-chunks (K'=64).
template <int EPI, bool TRIPLE, bool PRE>
__global__ __launch_bounds__(256, 2) void gemm3_kernel(
    const unsigned short* __restrict__ A3, size_t strideA,
    const float* __restrict__ B, int ldb,
    const unsigned short* __restrict__ B3, size_t strideB, int ldbk,
    float* Cf, unsigned short* C3, size_t strideC,
    const float* aux, int K, int ldc) {
    __shared__ unsigned short As[3][128][40];  // [plane][m][k], +8 pad
    __shared__ unsigned short Bs[3][64][40];   // [plane][n][k], +8 pad

    int tid = threadIdx.x;
    int wv = tid >> 6, lane = tid & 63;
    int wr = wv >> 1, wc = wv & 1;
    int mblk = blockIdx.y * 128, nblk = blockIdx.x * 64;

    f32x4 acc[4][2];
    double accd[4][2][4];
#pragma unroll
    for (int mt = 0; mt < 4; mt++)
#pragma unroll
        for (int nt = 0; nt < 2; nt++) {
            acc[mt][nt] = (f32x4){0.f, 0.f, 0.f, 0.f};
#pragma unroll
            for (int r = 0; r < 4; r++) accd[mt][nt][r] = 0.0;
        }

    int rA = lane & 15;
    int kq = (lane >> 4) << 3;

    for (int k0 = 0, c = 0; k0 < K; k0 += 32, ++c) {
        // ---- stage A: pre-split bf16 planes (k-contiguous, b128) ----
#pragma unroll
        for (int pl = 0; pl < 3; pl++) {
#pragma unroll
            for (int r = 0; r < 2; r++) {
                int idx = tid + r * 256;  // 0..511
                int row = idx >> 2, kg = (idx & 3) << 3;
                const unsigned short* src =
                    A3 + (size_t)pl * strideA + (size_t)(mblk + row) * K + k0 + kg;
                *(uint4*)(&As[pl][row][kg]) = *(const uint4*)src;
            }
        }
        // ---- stage B ----
        if (PRE) {
#pragma unroll
            for (int pl = 0; pl < 3; pl++) {
                int row = tid >> 2, kg = (tid & 3) << 3;
                const unsigned short* src =
                    B3 + (size_t)pl * strideB + (size_t)(nblk + row) * ldbk + k0 + kg;
                *(uint4*)(&Bs[pl][row][kg]) = *(const uint4*)src;
            }
        } else {
#pragma unroll
            for (int r = 0; r < 2; r++) {
                int idx = tid + r * 256;  // 0..511
                int kk = idx >> 4, ng = (idx & 15) << 2;
                float4 bv = *(const float4*)(B + (size_t)(k0 + kk) * ldb + nblk + ng);
                float xv[4] = {bv.x, bv.y, bv.z, bv.w};
#pragma unroll
                for (int cc = 0; cc < 4; cc++) {
                    unsigned short h, m, l;
                    split3(xv[cc], h, m, l);
                    Bs[0][ng + cc][kk] = h;
                    Bs[1][ng + cc][kk] = m;
                    Bs[2][ng + cc][kk] = l;
                }
            }
        }
        __syncthreads();

        // ---- fragments ----
        bf16x8 Af[3][4], Bf[3][2];
#pragma unroll
        for (int pl = 0; pl < 3; pl++) {
#pragma unroll
            for (int mt = 0; mt < 4; mt++)
                Af[pl][mt] = *(const bf16x8*)(&As[pl][wr * 64 + mt * 16 + rA][kq]);
#pragma unroll
            for (int nt = 0; nt < 2; nt++)
                Bf[pl][nt] = *(const bf16x8*)(&Bs[pl][wc * 32 + nt * 16 + rA][kq]);
        }
        // ---- 6 MFMA products per tile ----
#pragma unroll
        for (int mt = 0; mt < 4; mt++)
#pragma unroll
            for (int nt = 0; nt < 2; nt++) {
                f32x4 a = acc[mt][nt];
                a = __builtin_amdgcn_mfma_f32_16x16x32_bf16(Af[0][mt], Bf[0][nt], a, 0, 0, 0);
                a = __builtin_amdgcn_mfma_f32_16x16x32_bf16(Af[0][mt], Bf[1][nt], a, 0, 0, 0);
                a = __builtin_amdgcn_mfma_f32_16x16x32_bf16(Af[1][mt], Bf[0][nt], a, 0, 0, 0);
                a = __builtin_amdgcn_mfma_f32_16x16x32_bf16(Af[1][mt], Bf[1][nt], a, 0, 0, 0);
                a = __builtin_amdgcn_mfma_f32_16x16x32_bf16(Af[0][mt], Bf[2][nt], a, 0, 0, 0);
                a = __builtin_amdgcn_mfma_f32_16x16x32_bf16(Af[2][mt], Bf[0][nt], a, 0, 0, 0);
                acc[mt][nt] = a;
            }
        __syncthreads();

        // ---- promote fp32 -> f64 every 2 chunks (K'=64) ----
        if (c & 1) {
#pragma unroll
            for (int mt = 0; mt < 4; mt++)
#pragma unroll
                for (int nt = 0; nt < 2; nt++)
#pragma unroll
                    for (int r = 0; r < 4; r++) {
                        accd[mt][nt][r] += (double)acc[mt][nt][r];
                        acc[mt][nt][r] = 0.f;
                    }
        }
    }

    // ---- epilogue (f64), write f32 or bf16-triple ----
#pragma unroll
    for (int mt = 0; mt < 4; mt++)
#pragma unroll
        for (int nt = 0; nt < 2; nt++) {
            int n = nblk + wc * 32 + nt * 16 + (lane & 15);
            int mb = mblk + wr * 64 + mt * 16 + ((lane >> 4) << 2);
#pragma unroll
            for (int r = 0; r < 4; r++) {
                int m = mb + r;
                size_t off = (size_t)m * ldc + n;
                double v = accd[mt][nt][r];
                if (EPI == EPI_ADD) v += (double)aux[off];
                if (EPI == EPI_SILU) {
                    float vf = (float)v;
                    v = (double)(vf / (1.0f + expf(-vf)));
                }
                if (EPI == EPI_MUL) v *= (double)aux[off];
                if (EPI == EPI_BIAS) v += (double)aux[n];
                if (TRIPLE) {
                    unsigned short h, mm, l;
                    split3((float)v, h, mm, l);
                    C3[off] = h;
                    C3[strideC + off] = mm;
                    C3[2 * strideC + off] = l;
                } else {
                    Cf[off] = (float)v;
                }
            }
        }
}

// ---------------- Argmax over f32 logits (first-max tie-break) ----------------
__global__ __launch_bounds__(256) void argmax_kernel(const float* __restrict__ logits,
                                                     int* __restrict__ out_tok, int p) {
    int t = blockIdx.x;
    const float* lr = logits + (size_t)t * Vn;
    float bv = -INFINITY;
    int bi = 0x7fffffff;
    for (int j = threadIdx.x; j < Vn; j += 256) {
        float v = lr[j];
        if (v > bv || (v == bv && j < bi)) {
            bv = v;
            bi = j;
        }
    }
#pragma unroll
    for (int o = 1; o < 64; o <<= 1) {
        float ov = __shfl_xor(bv, o, 64);
        int oi = __shfl_xor(bi, o, 64);
        if (ov > bv || (ov == bv && oi < bi)) {
            bv = ov;
            bi = oi;
        }
    }
    __shared__ float sv[4];
    __shared__ int si[4];
    if ((threadIdx.x & 63) == 0) {
        sv[threadIdx.x >> 6] = bv;
        si[threadIdx.x >> 6] = bi;
    }
    __syncthreads();
    if (threadIdx.x == 0) {
        for (int w = 1; w < 4; w++) {
            if (sv[w] > bv || (sv[w] == bv && si[w] < bi)) {
                bv = sv[w];
                bi = si[w];
            }
        }
        out_tok[(size_t)t * NSTEPSn + p] = bi;
    }
}

// ---------------- Embedding gather ----------------
__global__ __launch_bounds__(256) void embed_kernel(const float* __restrict__ E,
                                                    const int* __restrict__ toks,
                                                    float* __restrict__ x, int p) {
    int t = blockIdx.x;
    int tok = toks[(size_t)t * NSTEPSn + p];
    float4 v = ((const float4*)(E + (size_t)tok * Hn))[threadIdx.x];
    ((float4*)(x + (size_t)t * Hn))[threadIdx.x] = v;
}

extern "C" void kernel_launch(void* const* d_in, const int* in_sizes, int n_in,
                              void* d_out, int out_size, void* d_ws, size_t ws_size,
                              hipStream_t stream) {
    const float* x0 = (const float*)d_in[0];
    const float* Wq = (const float*)d_in[1];
    const float* Wk = (const float*)d_in[2];
    const float* Wv = (const float*)d_in[3];
    const float* Wo = (const float*)d_in[4];
    const float* Wg = (const float*)d_in[5];
    const float* Wu = (const float*)d_in[6];
    const float* Wd = (const float*)d_in[7];
    const float* n1 = (const float*)d_in[8];
    const float* n2 = (const float*)d_in[9];
    const float* Emb = (const float*)d_in[10];
    const float* Wout = (const float*)d_in[11];
    const float* bout = (const float*)d_in[12];
    int* toks = (int*)d_out;

    float* ws = (float*)d_ws;
    const size_t M1 = 1024 * 1024;
    float* EK = ws;                  // V x H fp32           4MB
    float* EV = ws + 1 * M1;         //                      4MB
    float* K0 = ws + 2 * M1;         // T x H fp32           16MB
    float* V0 = ws + 6 * M1;         //                      16MB
    float* xb = ws + 10 * M1;        // residual hidden      16MB
    float* qb = ws + 14 * M1;        // q / MLP acc / logits 16MB
    float* Gc = ws + 18 * M1;        // silu chunk fp32      16MB
    unsigned short* s3a = (unsigned short*)(ws + 22 * M1);  // triple TxH  24MB
    unsigned short* s3g = (unsigned short*)(ws + 28 * M1);  // triple TxH  24MB
    double2* tab = (double2*)(ws + 34 * M1);                // 256 double2  4KB
    unsigned short* Wg3 = (unsigned short*)(ws + 34 * M1 + 1024);  // 24MB
    unsigned short* Wu3 = Wg3 + 12 * M1;                           // 24MB
    unsigned short* Wd3 = Wu3 + 12 * M1;                           // 24MB
    // total = 52M floats + 4KB = 208 MB

    const size_t STH = (size_t)Tn * Hn;  // plane stride, T x 1024 triples
    const size_t SVH = (size_t)Vn * Hn;  // plane stride, V x H triple
    const size_t SW = (size_t)4 * M1;    // plane stride, 4M-element weights

    dim3 blk(256);
    dim3 gTH(Hn / 64, Tn / 128);  // (16, 32): M=T, N=1024
    dim3 gVH(Hn / 64, Vn / 128);  // (16, 8):  M=V, N=1024

    // ---- One-time precompute: RoPE table, MLP weight pre-split, EK/EV ----
    rope_tab_kernel<<<1, 256, 0, stream>>>(tab);
    presplit_kernel<<<dim3(In / 64, Hn / 64), blk, 0, stream>>>(Wg, Wg3, Hn, In);
    presplit_kernel<<<dim3(In / 64, Hn / 64), blk, 0, stream>>>(Wu, Wu3, Hn, In);
    presplit_kernel<<<dim3(Hn / 64, In / 64), blk, 0, stream>>>(Wd, Wd3, In, Hn);
    rmsnorm3_kernel<<<Vn, 256, 0, stream>>>(Emb, n1, s3a, SVH);
    gemm3_kernel<EPI_NONE, false, false><<<gVH, blk, 0, stream>>>(
        s3a, SVH, Wk, Hn, nullptr, 0, 0, EK, nullptr, 0, nullptr, Hn, Hn);
    gemm3_kernel<EPI_NONE, false, false><<<gVH, blk, 0, stream>>>(
        s3a, SVH, Wv, Hn, nullptr, 0, 0, EV, nullptr, 0, nullptr, Hn, Hn);

    for (int p = 0; p < NSTEPSn; p++) {
        const float* src = (p == 0) ? x0 : xb;

        rmsnorm3_kernel<<<Tn, 256, 0, stream>>>(src, n1, s3a, STH);
        gemm3_kernel<EPI_NONE, false, false><<<gTH, blk, 0, stream>>>(
            s3a, STH, Wq, Hn, nullptr, 0, 0, qb, nullptr, 0, nullptr, Hn, Hn);
        if (p == 0) {
            gemm3_kernel<EPI_NONE, false, false><<<gTH, blk, 0, stream>>>(
                s3a, STH, Wk, Hn, nullptr, 0, 0, K0, nullptr, 0, nullptr, Hn, Hn);
            gemm3_kernel<EPI_NONE, false, false><<<gTH, blk, 0, stream>>>(
                s3a, STH, Wv, Hn, nullptr, 0, 0, V0, nullptr, 0, nullptr, Hn, Hn);
        }
        attn_kernel<<<(Tn * NHn) / 4, 256, 0, stream>>>(qb, K0, V0, EK, EV, toks,
                                                        tab, s3a, STH, p);
        // h2 = ctx @ Wo + src  (in-place into xb when src == xb)
        gemm3_kernel<EPI_ADD, false, false><<<gTH, blk, 0, stream>>>(
            s3a, STH, Wo, Hn, nullptr, 0, 0, xb, nullptr, 0, src, Hn, Hn);
        rmsnorm3_kernel<<<Tn, 256, 0, stream>>>(xb, n2, s3a, STH);
        // Gated MLP, chunked over I (4 x 1024), pre-split weights; acc into qb.
        for (int c = 0; c < 4; c++) {
            gemm3_kernel<EPI_SILU, false, true><<<gTH, blk, 0, stream>>>(
                s3a, STH, nullptr, 0, Wg3 + (size_t)c * M1, SW, 1024,
                Gc, nullptr, 0, nullptr, Hn, 1024);
            gemm3_kernel<EPI_MUL, true, true><<<gTH, blk, 0, stream>>>(
                s3a, STH, nullptr, 0, Wu3 + (size_t)c * M1, SW, 1024,
                nullptr, s3g, STH, Gc, Hn, 1024);
            if (c < 3) {
                gemm3_kernel<EPI_ADD, false, true><<<gTH, blk, 0, stream>>>(
                    s3g, STH, nullptr, 0, Wd3 + (size_t)c * 1024, SW, 4096,
                    qb, nullptr, 0, (c == 0) ? xb : qb, 1024, Hn);
            } else {
                gemm3_kernel<EPI_ADD, true, true><<<gTH, blk, 0, stream>>>(
                    s3g, STH, nullptr, 0, Wd3 + (size_t)c * 1024, SW, 4096,
                    nullptr, s3a, STH, qb, 1024, Hn);
            }
        }
        // logits = out @ Wout + bout  (into qb)
        gemm3_kernel<EPI_BIAS, false, false><<<gTH, blk, 0, stream>>>(
            s3a, STH, Wout, Vn, nullptr, 0, 0, qb, nullptr, 0, bout, Hn, Vn);
        argmax_kernel<<<Tn, 256, 0, stream>>>(qb, toks, p);
        if (p < NSTEPSn - 1) embed_kernel<<<Tn, 256, 0, stream>>>(Emb, toks, xb, p);
    }
}